// Round 13
// baseline (711.852 us; speedup 1.0000x reference)
//
#include <hip/hip_runtime.h>

#define HD 128
#define RNUM 8
#define SCAN_BS 2048

typedef __attribute__((ext_vector_type(8))) short short8;
typedef __attribute__((ext_vector_type(4))) float float4e;

__device__ __forceinline__ unsigned short f2bf(float f) {
    unsigned int u = __float_as_uint(f);
    u += 0x7fffu + ((u >> 16) & 1u);   // RNE
    return (unsigned short)(u >> 16);
}

__device__ __forceinline__ unsigned int pk2(float lo, float hi) {
    return (unsigned int)f2bf(lo) | ((unsigned int)f2bf(hi) << 16);
}

// accumulate 2 bf16 packed in u into a[i], a[i+1]
__device__ __forceinline__ void acc2(float4e& a, unsigned int u, int i) {
    a[i]     += __uint_as_float(u << 16);
    a[i + 1] += __uint_as_float(u & 0xffff0000u);
}

// ---------------- small kernels ----------------
__global__ void zero_i(int* __restrict__ p, int n) {
    int g = blockIdx.x * blockDim.x + threadIdx.x;
    if (g < n) p[g] = 0;
}

// weights -> bf16 transposed WT[mat][f][d], plus emb -> bf16, one launch
__global__ void prep_kernel(const float* __restrict__ W1, const float* __restrict__ r1,
                            const float* __restrict__ W2, const float* __restrict__ r2,
                            unsigned short* __restrict__ WT,
                            const float* __restrict__ emb, unsigned short* __restrict__ emb16,
                            long long n8) {
    long long g = (long long)blockIdx.x * blockDim.x + threadIdx.x;
    if (g < 18 * 16384) {
        int gi = (int)g;
        int mat = gi >> 14;
        int idx = gi & 16383;
        int d = idx >> 7;
        int f = idx & 127;
        const float* src;
        int m;
        if (mat < 8)       { src = W1; m = mat; }
        else if (mat == 8) { src = r1; m = 0; }
        else if (mat < 17) { src = W2; m = mat - 9; }
        else               { src = r2; m = 0; }
        WT[mat * 16384 + f * 128 + d] = f2bf(src[(size_t)m * 16384 + d * 128 + f]);
    }
    long long h = g - 18 * 16384;
    if (h >= 0 && h < n8) {
        const float4* p = (const float4*)(emb + h * 8);
        float4 v0 = p[0], v1 = p[1];
        uint4 o;
        o.x = pk2(v0.x, v0.y);
        o.y = pk2(v0.z, v0.w);
        o.z = pk2(v1.x, v1.y);
        o.w = pk2(v1.z, v1.w);
        *(uint4*)(emb16 + h * 8) = o;
    }
}

// ---------------- CSR build (dst-major: seg = dst*8 + r) ----------------
__global__ void count_kernel(const int* __restrict__ ei, const int* __restrict__ et,
                             int* __restrict__ cnt, int E, int N) {
    int e = blockIdx.x * blockDim.x + threadIdx.x;
    if (e < E) atomicAdd(&cnt[ei[E + e] * RNUM + et[e]], 1);
}

__global__ void scan1(const int* __restrict__ in, int* __restrict__ out,
                      int* __restrict__ bsum, int n) {
    __shared__ int s[256];
    const int tid = threadIdx.x;
    const int base = blockIdx.x * SCAN_BS + tid * 8;
    int v[8];
    int sum = 0;
#pragma unroll
    for (int j = 0; j < 8; j++) {
        int x = (base + j < n) ? in[base + j] : 0;
        v[j] = sum;
        sum += x;
    }
    s[tid] = sum;
    __syncthreads();
    for (int off = 1; off < 256; off <<= 1) {
        int tv = (tid >= off) ? s[tid - off] : 0;
        __syncthreads();
        if (tid >= off) s[tid] += tv;
        __syncthreads();
    }
    int excl = (tid > 0) ? s[tid - 1] : 0;
    if (tid == 255) bsum[blockIdx.x] = s[255];
#pragma unroll
    for (int j = 0; j < 8; j++)
        if (base + j < n) out[base + j] = v[j] + excl;
}

__global__ void scan2(int* __restrict__ bsum, int nb) {
    __shared__ int s[512];
    const int tid = threadIdx.x;
    s[tid] = (tid < nb) ? bsum[tid] : 0;
    __syncthreads();
    for (int off = 1; off < 512; off <<= 1) {
        int tv = (tid >= off) ? s[tid - off] : 0;
        __syncthreads();
        if (tid >= off) s[tid] += tv;
        __syncthreads();
    }
    if (tid < nb) bsum[tid] = (tid > 0) ? s[tid - 1] : 0;
}

__global__ void scan3(int* __restrict__ out, int* __restrict__ cur,
                      const int* __restrict__ bsum, int n) {
    const int base = blockIdx.x * SCAN_BS + threadIdx.x * 8;
    const int add = bsum[blockIdx.x];
#pragma unroll
    for (int j = 0; j < 8; j++) {
        int i = base + j;
        if (i < n) {
            int v = out[i] + add;
            out[i] = v;
            cur[i] = v;
        }
    }
}

// fill: col = src node id (layer 2), colE = pre-resolved entity id (layer 1).
// Thread 0 also writes the terminating boundary row_start[8*N] = E.
__global__ void fill_kernel(const int* __restrict__ ei, const int* __restrict__ et,
                            const int* __restrict__ ids,
                            int* __restrict__ cur, int* __restrict__ col,
                            int* __restrict__ colE, int* __restrict__ row_start,
                            int E, int N) {
    int e = blockIdx.x * blockDim.x + threadIdx.x;
    if (e == 0) row_start[RNUM * N] = E;
    if (e < E) {
        int src = ei[e];
        int pos = atomicAdd(&cur[ei[E + e] * RNUM + et[e]], 1);
        col[pos] = src;
        colE[pos] = ids[src];
    }
}

// ---------------- fused layer: barrier-free, one wave = one 16-row tile ----------------
// Zero LDS, zero __syncthreads. Lane l serves row (l&15), feature-slice q=(l>>4):
// walk accumulates features {k0*32 + q*8 .. +8} (= the exact 16x16x32 A-fragment
// this lane must hold), convert in-register, MFMA with B read directly from
// linear WT (L1/L2-hot; wave-independence hides the latency).
// 16 waves/CU x 16 rows = 256 concurrent edge walks per CU; walk-max coupling
// only within a wave (max of 16 Poisson draws), never across waves.
template <bool HAS_IDX, int ACT>   // ACT: 0 = relu -> bf16 out, 1 = sigmoid -> f32 out
__launch_bounds__(256, 4)
__global__ void rgcn_wave(const int* __restrict__ row_start, const int* __restrict__ col,
                          const int* __restrict__ ids,
                          const unsigned short* __restrict__ x16,
                          const unsigned short* __restrict__ WT,
                          const float* __restrict__ bias,
                          void* __restrict__ CoutV, int N, int E) {
    const int lane = threadIdx.x & 63;
    const int waveId = blockIdx.x * (blockDim.x >> 6) + (threadIdx.x >> 6);
    const int base = waveId * 16;
    if (base >= N) return;                 // wave-uniform exit, no barriers in kernel
    const int rowl = lane & 15;
    const int q = lane >> 4;
    const int mydst = base + rowl;
    const bool rowok = (mydst < N);
    const int xoff = q * 8;                // short offset of this lane's 8-feature slice

    float4e acc[8];                        // C: 8 col-tiles x f32x4
#pragma unroll
    for (int j = 0; j < 8; j++) acc[j] = (float4e){0.f, 0.f, 0.f, 0.f};

    union U8 { uint4 u; short8 s; };

#pragma unroll 1
    for (int r = 0; r < RNUM + 1; r++) {
        U8 af0, af1, af2, af3;             // A-fragments for k0 = 0..3
        if (r < RNUM) {
            // ---- walk this row's relation-r segment (contiguous, dst-major) ----
            float4e a[8];
#pragma unroll
            for (int j = 0; j < 8; j++) a[j] = (float4e){0.f, 0.f, 0.f, 0.f};
            int s0 = 0, s1 = 0;
            if (rowok) {
                s0 = row_start[mydst * 8 + r];
                s1 = row_start[mydst * 8 + r + 1];
            }
            const float inv = (s1 > s0) ? 1.0f / (float)(s1 - s0) : 0.0f;
#pragma unroll 1
            for (int e = s0; e < s1; e++) {
                int c = col[e];
                const unsigned short* xr = x16 + (size_t)c * HD + xoff;
                uint4 v0 = *(const uint4*)(xr);        // feats k0=0: q*8..+8
                uint4 v1 = *(const uint4*)(xr + 32);   // k0=1
                uint4 v2 = *(const uint4*)(xr + 64);   // k0=2
                uint4 v3 = *(const uint4*)(xr + 96);   // k0=3
                acc2(a[0], v0.x, 0); acc2(a[0], v0.y, 2);
                acc2(a[1], v0.z, 0); acc2(a[1], v0.w, 2);
                acc2(a[2], v1.x, 0); acc2(a[2], v1.y, 2);
                acc2(a[3], v1.z, 0); acc2(a[3], v1.w, 2);
                acc2(a[4], v2.x, 0); acc2(a[4], v2.y, 2);
                acc2(a[5], v2.z, 0); acc2(a[5], v2.w, 2);
                acc2(a[6], v3.x, 0); acc2(a[6], v3.y, 2);
                acc2(a[7], v3.z, 0); acc2(a[7], v3.w, 2);
            }
#pragma unroll
            for (int j = 0; j < 8; j++) a[j] *= inv;
            af0.u = (uint4){pk2(a[0][0], a[0][1]), pk2(a[0][2], a[0][3]),
                            pk2(a[1][0], a[1][1]), pk2(a[1][2], a[1][3])};
            af1.u = (uint4){pk2(a[2][0], a[2][1]), pk2(a[2][2], a[2][3]),
                            pk2(a[3][0], a[3][1]), pk2(a[3][2], a[3][3])};
            af2.u = (uint4){pk2(a[4][0], a[4][1]), pk2(a[4][2], a[4][3]),
                            pk2(a[5][0], a[5][1]), pk2(a[5][2], a[5][3])};
            af3.u = (uint4){pk2(a[6][0], a[6][1]), pk2(a[6][2], a[6][3]),
                            pk2(a[7][0], a[7][1]), pk2(a[7][2], a[7][3])};
        } else {
            // ---- root/self term: direct bf16 row copy (ids gather for layer 1) ----
            uint4 r0 = {0u, 0u, 0u, 0u}, r1 = r0, r2 = r0, r3 = r0;
            if (rowok) {
                int srcn = HAS_IDX ? ids[mydst] : mydst;
                const unsigned short* xr = x16 + (size_t)srcn * HD + xoff;
                r0 = *(const uint4*)(xr);
                r1 = *(const uint4*)(xr + 32);
                r2 = *(const uint4*)(xr + 64);
                r3 = *(const uint4*)(xr + 96);
            }
            af0.u = r0; af1.u = r1; af2.u = r2; af3.u = r3;
        }

        // ---- MFMA: B-fragments straight from linear WT (no LDS) ----
        // b for (ct,k0): WT_r[(ct*16 + rowl)*128 + k0*32 + q*8], 16 B each.
        const unsigned short* Wr = WT + r * 16384 + rowl * 128 + xoff;
#pragma unroll
        for (int ct = 0; ct < 8; ct++) {
            const unsigned short* wb = Wr + ct * 2048;
            short8 b0 = *(const short8*)(wb);
            short8 b1 = *(const short8*)(wb + 32);
            short8 b2 = *(const short8*)(wb + 64);
            short8 b3 = *(const short8*)(wb + 96);
            acc[ct] = __builtin_amdgcn_mfma_f32_16x16x32_bf16(af0.s, b0, acc[ct], 0, 0, 0);
            acc[ct] = __builtin_amdgcn_mfma_f32_16x16x32_bf16(af1.s, b1, acc[ct], 0, 0, 0);
            acc[ct] = __builtin_amdgcn_mfma_f32_16x16x32_bf16(af2.s, b2, acc[ct], 0, 0, 0);
            acc[ct] = __builtin_amdgcn_mfma_f32_16x16x32_bf16(af3.s, b3, acc[ct], 0, 0, 0);
        }
    }

    // ---- epilogue: C layout col = lane&15, row = q*4 + rg ----
#pragma unroll
    for (int ct = 0; ct < 8; ct++) {
        const int ncol = ct * 16 + rowl;
        const float bv = bias[ncol];
#pragma unroll
        for (int rg = 0; rg < 4; rg++) {
            const int rowg = base + q * 4 + rg;
            if (rowg < N) {
                float v = acc[ct][rg] + bv;
                if (ACT == 0) {
                    v = fmaxf(v, 0.0f);
                    ((unsigned short*)CoutV)[(size_t)rowg * HD + ncol] = f2bf(v);
                } else {
                    v = 1.0f / (1.0f + expf(-v));
                    ((float*)CoutV)[(size_t)rowg * HD + ncol] = v;
                }
            }
        }
    }
}

extern "C" void kernel_launch(void* const* d_in, const int* in_sizes, int n_in,
                              void* d_out, int out_size, void* d_ws, size_t ws_size,
                              hipStream_t stream) {
    const int*   x_ids = (const int*)d_in[0];
    const int*   ei    = (const int*)d_in[1];
    const int*   et    = (const int*)d_in[2];
    const float* emb   = (const float*)d_in[3];
    const float* W1    = (const float*)d_in[4];
    const float* root1 = (const float*)d_in[5];
    const float* b1    = (const float*)d_in[6];
    const float* W2    = (const float*)d_in[7];
    const float* root2 = (const float*)d_in[8];
    const float* b2    = (const float*)d_in[9];

    const int N = in_sizes[0];
    const int E = in_sizes[1] / 2;
    const int NS = RNUM * N;
    const long long embElems = (long long)in_sizes[3];   // NUM_ENTITIES * HD
    float* out = (float*)d_out;

    // ---- arenas (row_start has NS+1 entries, padded to 16 B) ----
    char* ws = (char*)d_ws;
    size_t off = 0;
    int* row_start = (int*)(ws + off); off += (size_t)(NS + 4) * 4;             // 3.2 MB
    int* col       = (int*)(ws + off); off += (size_t)E * 4;                    // 2.0 MB
    int* colE      = (int*)(ws + off); off += (size_t)E * 4;                    // 2.0 MB
    int* bsum      = (int*)(ws + off); off += 4096;
    unsigned short* WT    = (unsigned short*)(ws + off); off += (size_t)18 * 16384 * 2;
    unsigned short* emb16 = (unsigned short*)(ws + off); off += (size_t)embElems * 2;  // 25.6 MB
    unsigned short* z16   = (unsigned short*)(ws + off); off += (size_t)N * HD * 2;    // 25.6 MB
    int* cur = (int*)z16;   // alias: cur dead before z16 is first written

    const int scanBlocks = (NS + SCAN_BS - 1) / SCAN_BS;
    const int nWaves = (N + 15) / 16;
    const int layerGrid = (nWaves + 3) / 4;   // 4 waves (256 threads) per block

    // ---- CSR build (dst-major) ----
    zero_i<<<(NS + 255) / 256, 256, 0, stream>>>(cur, NS);
    count_kernel<<<(E + 255) / 256, 256, 0, stream>>>(ei, et, cur, E, N);
    scan1<<<scanBlocks, 256, 0, stream>>>(cur, row_start, bsum, NS);
    scan2<<<1, 512, 0, stream>>>(bsum, scanBlocks);
    scan3<<<scanBlocks, 256, 0, stream>>>(row_start, cur, bsum, NS);
    fill_kernel<<<(E + 255) / 256, 256, 0, stream>>>(ei, et, x_ids, cur, col, colE,
                                                     row_start, E, N);

    // ---- weights -> bf16 transposed + emb -> bf16 (one launch) ----
    {
        long long n8 = embElems / 8;
        long long total = 18 * 16384 + n8;
        prep_kernel<<<(unsigned int)((total + 255) / 256), 256, 0, stream>>>(
            W1, root1, W2, root2, WT, emb, emb16, n8);
    }

    // ---- layer 1: z16 = bf16(relu(agg(emb16) + emb16[ids]@root1 + b1)) ----
    rgcn_wave<true, 0><<<layerGrid, 256, 0, stream>>>(
        row_start, colE, x_ids, emb16, WT, b1, (void*)z16, N, E);
    // ---- layer 2: out = sigmoid(agg(z16) + z16@root2 + b2) ----
    rgcn_wave<false, 1><<<layerGrid, 256, 0, stream>>>(
        row_start, col, nullptr, z16, WT + 9 * 16384, b2, (void*)out, N, E);
}

// Round 14
// 440.760 us; speedup vs baseline: 1.6151x; 1.6151x over previous
//
#include <hip/hip_runtime.h>

#define HD 128
#define RNUM 8
#define SCAN_BS 2048

typedef __attribute__((ext_vector_type(8))) short short8;
typedef __attribute__((ext_vector_type(4))) float float4e;

__device__ __forceinline__ unsigned short f2bf(float f) {
    unsigned int u = __float_as_uint(f);
    u += 0x7fffu + ((u >> 16) & 1u);   // RNE
    return (unsigned short)(u >> 16);
}

__device__ __forceinline__ unsigned int pk2(float lo, float hi) {
    return (unsigned int)f2bf(lo) | ((unsigned int)f2bf(hi) << 16);
}

// accumulate 2 bf16 packed in u into a[i], a[i+1]
__device__ __forceinline__ void acc2(float4e& a, unsigned int u, int i) {
    a[i]     += __uint_as_float(u << 16);
    a[i + 1] += __uint_as_float(u & 0xffff0000u);
}

// ---------------- small kernels ----------------
__global__ void zero_i(int* __restrict__ p, int n) {
    int g = blockIdx.x * blockDim.x + threadIdx.x;
    if (g < n) p[g] = 0;
}

// weights -> bf16 transposed WT[mat][f][d], emb -> bf16, zero tile counters
__global__ void prep_kernel(const float* __restrict__ W1, const float* __restrict__ r1,
                            const float* __restrict__ W2, const float* __restrict__ r2,
                            unsigned short* __restrict__ WT,
                            const float* __restrict__ emb, unsigned short* __restrict__ emb16,
                            int* __restrict__ tctr, long long n8) {
    long long g = (long long)blockIdx.x * blockDim.x + threadIdx.x;
    if (g == 0) { tctr[0] = 0; tctr[1] = 0; }
    if (g < 18 * 16384) {
        int gi = (int)g;
        int mat = gi >> 14;
        int idx = gi & 16383;
        int d = idx >> 7;
        int f = idx & 127;
        const float* src;
        int m;
        if (mat < 8)       { src = W1; m = mat; }
        else if (mat == 8) { src = r1; m = 0; }
        else if (mat < 17) { src = W2; m = mat - 9; }
        else               { src = r2; m = 0; }
        WT[mat * 16384 + f * 128 + d] = f2bf(src[(size_t)m * 16384 + d * 128 + f]);
    }
    long long h = g - 18 * 16384;
    if (h >= 0 && h < n8) {
        const float4* p = (const float4*)(emb + h * 8);
        float4 v0 = p[0], v1 = p[1];
        uint4 o;
        o.x = pk2(v0.x, v0.y);
        o.y = pk2(v0.z, v0.w);
        o.z = pk2(v1.x, v1.y);
        o.w = pk2(v1.z, v1.w);
        *(uint4*)(emb16 + h * 8) = o;
    }
}

// ---------------- CSR build (dst-major: seg = dst*8 + r) ----------------
__global__ void count_kernel(const int* __restrict__ ei, const int* __restrict__ et,
                             int* __restrict__ cnt, int E, int N) {
    int e = blockIdx.x * blockDim.x + threadIdx.x;
    if (e < E) atomicAdd(&cnt[ei[E + e] * RNUM + et[e]], 1);
}

__global__ void scan1(const int* __restrict__ in, int* __restrict__ out,
                      int* __restrict__ bsum, int n) {
    __shared__ int s[256];
    const int tid = threadIdx.x;
    const int base = blockIdx.x * SCAN_BS + tid * 8;
    int v[8];
    int sum = 0;
#pragma unroll
    for (int j = 0; j < 8; j++) {
        int x = (base + j < n) ? in[base + j] : 0;
        v[j] = sum;
        sum += x;
    }
    s[tid] = sum;
    __syncthreads();
    for (int off = 1; off < 256; off <<= 1) {
        int tv = (tid >= off) ? s[tid - off] : 0;
        __syncthreads();
        if (tid >= off) s[tid] += tv;
        __syncthreads();
    }
    int excl = (tid > 0) ? s[tid - 1] : 0;
    if (tid == 255) bsum[blockIdx.x] = s[255];
#pragma unroll
    for (int j = 0; j < 8; j++)
        if (base + j < n) out[base + j] = v[j] + excl;
}

__global__ void scan2(int* __restrict__ bsum, int nb) {
    __shared__ int s[512];
    const int tid = threadIdx.x;
    s[tid] = (tid < nb) ? bsum[tid] : 0;
    __syncthreads();
    for (int off = 1; off < 512; off <<= 1) {
        int tv = (tid >= off) ? s[tid - off] : 0;
        __syncthreads();
        if (tid >= off) s[tid] += tv;
        __syncthreads();
    }
    if (tid < nb) bsum[tid] = (tid > 0) ? s[tid - 1] : 0;
}

__global__ void scan3(int* __restrict__ out, int* __restrict__ cur,
                      const int* __restrict__ bsum, int n) {
    const int base = blockIdx.x * SCAN_BS + threadIdx.x * 8;
    const int add = bsum[blockIdx.x];
#pragma unroll
    for (int j = 0; j < 8; j++) {
        int i = base + j;
        if (i < n) {
            int v = out[i] + add;
            out[i] = v;
            cur[i] = v;
        }
    }
}

// fill: col = src node id (layer 2), colE = pre-resolved entity id (layer 1).
// Thread 0 also writes the terminating boundary row_start[8*N] = E.
__global__ void fill_kernel(const int* __restrict__ ei, const int* __restrict__ et,
                            const int* __restrict__ ids,
                            int* __restrict__ cur, int* __restrict__ col,
                            int* __restrict__ colE, int* __restrict__ row_start,
                            int E, int N) {
    int e = blockIdx.x * blockDim.x + threadIdx.x;
    if (e == 0) row_start[RNUM * N] = E;
    if (e < E) {
        int src = ei[e];
        int pos = atomicAdd(&cur[ei[E + e] * RNUM + et[e]], 1);
        col[pos] = src;
        colE[pos] = ids[src];
    }
}

// ---------------- fused layer: 512 threads, 128-row tiles, work-stealing ----------------
// LDS = As only (32 KB). B-fragments prefetched to registers right after the walk
// (L2 latency hides under the barrier's walk-straggler wait). Walk uses a 2-deep
// rotate pipeline (issue x-row e+1 while accumulating e) -> ~2x on the serial chain.
// Dynamic tile pop via global counter kills the dispatch-round tail.
template <bool HAS_IDX, int ACT>   // ACT: 0 = relu -> bf16 out, 1 = sigmoid -> f32 out
__launch_bounds__(512, 4)
__global__ void rgcn_fused(const int* __restrict__ row_start, const int* __restrict__ col,
                           const int* __restrict__ ids,
                           const unsigned short* __restrict__ x16,
                           const unsigned short* __restrict__ WT,
                           const float* __restrict__ bias,
                           int* __restrict__ tctr, int numTiles,
                           void* __restrict__ CoutV, int N, int E) {
    __shared__ unsigned short As[128 * 128];   // 32 KB
    __shared__ int tileShare;

    const int tid = threadIdx.x;
    // MFMA mapping (8 waves: 2 row strips of 64 x 4 col strips of 32)
    const int w = tid >> 6;
    const int lane = tid & 63;
    const int ln15 = lane & 15;
    const int quad = lane >> 4;
    const int rowbase = (w & 1) * 64;
    const int colbase = (w >> 1) * 32;
    // walk mapping: 128 groups of 4 lanes; group g owns row g (64 B per lane)
    const int grp = tid >> 2;
    const int sub4 = tid & 3;

    for (;;) {
        if (tid == 0) tileShare = atomicAdd(tctr, 1);
        __syncthreads();
        const int tile = tileShare;
        if (tile >= numTiles) break;
        const int block0 = tile * 128;
        const int mydst = block0 + grp;
        const bool rowok = (mydst < N);

        float4e acc[4][2];
#pragma unroll
        for (int i = 0; i < 4; i++)
#pragma unroll
            for (int j = 0; j < 2; j++)
#pragma unroll
                for (int q = 0; q < 4; q++) acc[i][j][q] = 0.0f;

#pragma unroll 1
        for (int s = 0; s < RNUM + 1; s++) {
            // ---- stage A tile ----
            if (s < RNUM) {
                float4e a[8];
#pragma unroll
                for (int j = 0; j < 8; j++) a[j] = (float4e){0.f, 0.f, 0.f, 0.f};
                int s0 = 0, s1 = 0;
                if (rowok) {
                    s0 = row_start[mydst * 8 + s];
                    s1 = row_start[mydst * 8 + s + 1];
                }
                const float inv = (s1 > s0) ? 1.0f / (float)(s1 - s0) : 0.0f;
                if (s1 > s0) {
                    // 2-deep rotate: x-row of edge e+1 in flight while accumulating e
                    const uint4* xp = (const uint4*)(x16 + (size_t)col[s0] * HD + sub4 * 32);
                    uint4 w0 = xp[0], w1 = xp[1], w2 = xp[2], w3 = xp[3];
#pragma unroll 1
                    for (int e = s0 + 1; e < s1; e++) {
                        const uint4* xq = (const uint4*)(x16 + (size_t)col[e] * HD + sub4 * 32);
                        uint4 n0 = xq[0], n1 = xq[1], n2 = xq[2], n3 = xq[3];
                        acc2(a[0], w0.x, 0); acc2(a[0], w0.y, 2);
                        acc2(a[1], w0.z, 0); acc2(a[1], w0.w, 2);
                        acc2(a[2], w1.x, 0); acc2(a[2], w1.y, 2);
                        acc2(a[3], w1.z, 0); acc2(a[3], w1.w, 2);
                        acc2(a[4], w2.x, 0); acc2(a[4], w2.y, 2);
                        acc2(a[5], w2.z, 0); acc2(a[5], w2.w, 2);
                        acc2(a[6], w3.x, 0); acc2(a[6], w3.y, 2);
                        acc2(a[7], w3.z, 0); acc2(a[7], w3.w, 2);
                        w0 = n0; w1 = n1; w2 = n2; w3 = n3;
                    }
                    acc2(a[0], w0.x, 0); acc2(a[0], w0.y, 2);
                    acc2(a[1], w0.z, 0); acc2(a[1], w0.w, 2);
                    acc2(a[2], w1.x, 0); acc2(a[2], w1.y, 2);
                    acc2(a[3], w1.z, 0); acc2(a[3], w1.w, 2);
                    acc2(a[4], w2.x, 0); acc2(a[4], w2.y, 2);
                    acc2(a[5], w2.z, 0); acc2(a[5], w2.w, 2);
                    acc2(a[6], w3.x, 0); acc2(a[6], w3.y, 2);
                    acc2(a[7], w3.z, 0); acc2(a[7], w3.w, 2);
                }
#pragma unroll
                for (int j = 0; j < 8; j++) a[j] *= inv;
#pragma unroll
                for (int j = 0; j < 4; j++) {
                    uint4 o;
                    o.x = pk2(a[2 * j][0], a[2 * j][1]);
                    o.y = pk2(a[2 * j][2], a[2 * j][3]);
                    o.z = pk2(a[2 * j + 1][0], a[2 * j + 1][1]);
                    o.w = pk2(a[2 * j + 1][2], a[2 * j + 1][3]);
                    int ck = sub4 * 4 + j;
                    *(uint4*)&As[grp * 128 + ((ck ^ (grp & 15)) << 3)] = o;
                }
            } else {
                // root/self term: bf16 row copy (gather through ids for layer 1)
                uint4 o0 = {0u, 0u, 0u, 0u}, o1 = o0, o2 = o0, o3 = o0;
                if (rowok) {
                    int srcn = HAS_IDX ? ids[mydst] : mydst;
                    const uint4* xp = (const uint4*)(x16 + (size_t)srcn * HD + sub4 * 32);
                    o0 = xp[0]; o1 = xp[1]; o2 = xp[2]; o3 = xp[3];
                }
                const int ck0 = sub4 * 4;
                *(uint4*)&As[grp * 128 + (((ck0 + 0) ^ (grp & 15)) << 3)] = o0;
                *(uint4*)&As[grp * 128 + (((ck0 + 1) ^ (grp & 15)) << 3)] = o1;
                *(uint4*)&As[grp * 128 + (((ck0 + 2) ^ (grp & 15)) << 3)] = o2;
                *(uint4*)&As[grp * 128 + (((ck0 + 3) ^ (grp & 15)) << 3)] = o3;
            }

            // ---- prefetch B-fragments to registers (latency hides under barrier) ----
            short8 breg[2][4];
            {
                const unsigned short* Wb = WT + s * 16384;
#pragma unroll
                for (int ct = 0; ct < 2; ct++) {
                    const unsigned short* wn = Wb + (colbase + ct * 16 + ln15) * 128 + quad * 8;
#pragma unroll
                    for (int k0 = 0; k0 < 4; k0++)
                        breg[ct][k0] = *(const short8*)(wn + k0 * 32);
                }
            }
            __syncthreads();   // As visible to all waves

            // ---- MFMA: A from LDS, B from registers ----
#pragma unroll
            for (int k0 = 0; k0 < 4; k0++) {
                short8 af[4];
                const int ck = k0 * 4 + quad;
#pragma unroll
                for (int rt = 0; rt < 4; rt++) {
                    int m = rowbase + rt * 16 + ln15;
                    af[rt] = *(const short8*)&As[m * 128 + ((ck ^ (m & 15)) << 3)];
                }
#pragma unroll
                for (int rt = 0; rt < 4; rt++)
#pragma unroll
                    for (int ct = 0; ct < 2; ct++)
                        acc[rt][ct] = __builtin_amdgcn_mfma_f32_16x16x32_bf16(
                            af[rt], breg[ct][k0], acc[rt][ct], 0, 0, 0);
            }
            __syncthreads();   // all waves done reading As
        }

        // ---- epilogue ----
#pragma unroll
        for (int ct = 0; ct < 2; ct++) {
            int ncol = colbase + ct * 16 + ln15;
            float bv = bias[ncol];
#pragma unroll
            for (int rt = 0; rt < 4; rt++) {
#pragma unroll
                for (int rg = 0; rg < 4; rg++) {
                    int rowg = block0 + rowbase + rt * 16 + quad * 4 + rg;
                    if (rowg < N) {
                        float v = acc[rt][ct][rg] + bv;
                        if (ACT == 0) {
                            v = fmaxf(v, 0.0f);
                            ((unsigned short*)CoutV)[(size_t)rowg * HD + ncol] = f2bf(v);
                        } else {
                            v = 1.0f / (1.0f + expf(-v));
                            ((float*)CoutV)[(size_t)rowg * HD + ncol] = v;
                        }
                    }
                }
            }
        }
    }
}

extern "C" void kernel_launch(void* const* d_in, const int* in_sizes, int n_in,
                              void* d_out, int out_size, void* d_ws, size_t ws_size,
                              hipStream_t stream) {
    const int*   x_ids = (const int*)d_in[0];
    const int*   ei    = (const int*)d_in[1];
    const int*   et    = (const int*)d_in[2];
    const float* emb   = (const float*)d_in[3];
    const float* W1    = (const float*)d_in[4];
    const float* root1 = (const float*)d_in[5];
    const float* b1    = (const float*)d_in[6];
    const float* W2    = (const float*)d_in[7];
    const float* root2 = (const float*)d_in[8];
    const float* b2    = (const float*)d_in[9];

    const int N = in_sizes[0];
    const int E = in_sizes[1] / 2;
    const int NS = RNUM * N;
    const long long embElems = (long long)in_sizes[3];   // NUM_ENTITIES * HD
    float* out = (float*)d_out;

    // ---- arenas (row_start has NS+1 entries, padded to 16 B) ----
    char* ws = (char*)d_ws;
    size_t off = 0;
    int* row_start = (int*)(ws + off); off += (size_t)(NS + 4) * 4;             // 3.2 MB
    int* col       = (int*)(ws + off); off += (size_t)E * 4;                    // 2.0 MB
    int* colE      = (int*)(ws + off); off += (size_t)E * 4;                    // 2.0 MB
    int* bsum      = (int*)(ws + off); off += 4096;                             // scan sums + tile ctrs
    unsigned short* WT    = (unsigned short*)(ws + off); off += (size_t)18 * 16384 * 2;
    unsigned short* emb16 = (unsigned short*)(ws + off); off += (size_t)embElems * 2;  // 25.6 MB
    unsigned short* z16   = (unsigned short*)(ws + off); off += (size_t)N * HD * 2;    // 25.6 MB
    int* cur  = (int*)z16;       // alias: cur dead before z16 is first written
    int* tctr = bsum + 1000;     // 2 tile counters (bsum uses only ~400 slots)

    const int scanBlocks = (NS + SCAN_BS - 1) / SCAN_BS;
    const int numTiles = (N + 127) / 128;
    const int layerGrid = (numTiles < 512) ? numTiles : 512;   // 2 blocks/CU, work-stealing

    // ---- CSR build (dst-major) ----
    zero_i<<<(NS + 255) / 256, 256, 0, stream>>>(cur, NS);
    count_kernel<<<(E + 255) / 256, 256, 0, stream>>>(ei, et, cur, E, N);
    scan1<<<scanBlocks, 256, 0, stream>>>(cur, row_start, bsum, NS);
    scan2<<<1, 512, 0, stream>>>(bsum, scanBlocks);
    scan3<<<scanBlocks, 256, 0, stream>>>(row_start, cur, bsum, NS);
    fill_kernel<<<(E + 255) / 256, 256, 0, stream>>>(ei, et, x_ids, cur, col, colE,
                                                     row_start, E, N);

    // ---- weights -> bf16 transposed + emb -> bf16 + zero tile counters (one launch) ----
    {
        long long n8 = embElems / 8;
        long long total = 18 * 16384 + n8;
        prep_kernel<<<(unsigned int)((total + 255) / 256), 256, 0, stream>>>(
            W1, root1, W2, root2, WT, emb, emb16, tctr, n8);
    }

    // ---- layer 1: z16 = bf16(relu(agg(emb16) + emb16[ids]@root1 + b1)) ----
    rgcn_fused<true, 0><<<layerGrid, 512, 0, stream>>>(
        row_start, colE, x_ids, emb16, WT, b1, tctr, numTiles, (void*)z16, N, E);
    // ---- layer 2: out = sigmoid(agg(z16) + z16@root2 + b2) ----
    rgcn_fused<false, 1><<<layerGrid, 512, 0, stream>>>(
        row_start, col, nullptr, z16, WT + 9 * 16384, b2, tctr + 1, numTiles, (void*)out, N, E);
}

// Round 16
// 388.997 us; speedup vs baseline: 1.8300x; 1.1331x over previous
//
#include <hip/hip_runtime.h>

#define HD 128
#define RNUM 8
#define SCAN_BS 2048

typedef __attribute__((ext_vector_type(8))) short short8;
typedef __attribute__((ext_vector_type(4))) float float4e;

__device__ __forceinline__ unsigned short f2bf(float f) {
    unsigned int u = __float_as_uint(f);
    u += 0x7fffu + ((u >> 16) & 1u);   // RNE
    return (unsigned short)(u >> 16);
}

__device__ __forceinline__ unsigned int pk2(float lo, float hi) {
    return (unsigned int)f2bf(lo) | ((unsigned int)f2bf(hi) << 16);
}

// accumulate 2 bf16 packed in u into a[i], a[i+1]
__device__ __forceinline__ void acc2(float4e& a, unsigned int u, int i) {
    a[i]     += __uint_as_float(u << 16);
    a[i + 1] += __uint_as_float(u & 0xffff0000u);
}

__device__ __forceinline__ void gload_lds16(const void* g, void* l) {
    __builtin_amdgcn_global_load_lds(
        (const __attribute__((address_space(1))) void*)g,
        (__attribute__((address_space(3))) void*)l, 16, 0, 0);
}

// ---------------- small kernels ----------------
__global__ void zero_i(int* __restrict__ p, int n) {
    int g = blockIdx.x * blockDim.x + threadIdx.x;
    if (g < n) p[g] = 0;
}

// weights -> bf16 transposed WT[mat][f][d], emb -> bf16, zero tile counters
__global__ void prep_kernel(const float* __restrict__ W1, const float* __restrict__ r1,
                            const float* __restrict__ W2, const float* __restrict__ r2,
                            unsigned short* __restrict__ WT,
                            const float* __restrict__ emb, unsigned short* __restrict__ emb16,
                            int* __restrict__ tctr, long long n8) {
    long long g = (long long)blockIdx.x * blockDim.x + threadIdx.x;
    if (g == 0) { tctr[0] = 0; tctr[1] = 0; }
    if (g < 18 * 16384) {
        int gi = (int)g;
        int mat = gi >> 14;
        int idx = gi & 16383;
        int d = idx >> 7;
        int f = idx & 127;
        const float* src;
        int m;
        if (mat < 8)       { src = W1; m = mat; }
        else if (mat == 8) { src = r1; m = 0; }
        else if (mat < 17) { src = W2; m = mat - 9; }
        else               { src = r2; m = 0; }
        WT[mat * 16384 + f * 128 + d] = f2bf(src[(size_t)m * 16384 + d * 128 + f]);
    }
    long long h = g - 18 * 16384;
    if (h >= 0 && h < n8) {
        const float4* p = (const float4*)(emb + h * 8);
        float4 v0 = p[0], v1 = p[1];
        uint4 o;
        o.x = pk2(v0.x, v0.y);
        o.y = pk2(v0.z, v0.w);
        o.z = pk2(v1.x, v1.y);
        o.w = pk2(v1.z, v1.w);
        *(uint4*)(emb16 + h * 8) = o;
    }
}

// ---------------- CSR build (dst-major: seg = dst*8 + r) ----------------
__global__ void count_kernel(const int* __restrict__ ei, const int* __restrict__ et,
                             int* __restrict__ cnt, int E, int N) {
    int e = blockIdx.x * blockDim.x + threadIdx.x;
    if (e < E) atomicAdd(&cnt[ei[E + e] * RNUM + et[e]], 1);
}

__global__ void scan1(const int* __restrict__ in, int* __restrict__ out,
                      int* __restrict__ bsum, int n) {
    __shared__ int s[256];
    const int tid = threadIdx.x;
    const int base = blockIdx.x * SCAN_BS + tid * 8;
    int v[8];
    int sum = 0;
#pragma unroll
    for (int j = 0; j < 8; j++) {
        int x = (base + j < n) ? in[base + j] : 0;
        v[j] = sum;
        sum += x;
    }
    s[tid] = sum;
    __syncthreads();
    for (int off = 1; off < 256; off <<= 1) {
        int tv = (tid >= off) ? s[tid - off] : 0;
        __syncthreads();
        if (tid >= off) s[tid] += tv;
        __syncthreads();
    }
    int excl = (tid > 0) ? s[tid - 1] : 0;
    if (tid == 255) bsum[blockIdx.x] = s[255];
#pragma unroll
    for (int j = 0; j < 8; j++)
        if (base + j < n) out[base + j] = v[j] + excl;
}

__global__ void scan2(int* __restrict__ bsum, int nb) {
    __shared__ int s[512];
    const int tid = threadIdx.x;
    s[tid] = (tid < nb) ? bsum[tid] : 0;
    __syncthreads();
    for (int off = 1; off < 512; off <<= 1) {
        int tv = (tid >= off) ? s[tid - off] : 0;
        __syncthreads();
        if (tid >= off) s[tid] += tv;
        __syncthreads();
    }
    if (tid < nb) bsum[tid] = (tid > 0) ? s[tid - 1] : 0;
}

__global__ void scan3(int* __restrict__ out, int* __restrict__ cur,
                      const int* __restrict__ bsum, int n) {
    const int base = blockIdx.x * SCAN_BS + threadIdx.x * 8;
    const int add = bsum[blockIdx.x];
#pragma unroll
    for (int j = 0; j < 8; j++) {
        int i = base + j;
        if (i < n) {
            int v = out[i] + add;
            out[i] = v;
            cur[i] = v;
        }
    }
}

// fill: col = src node id (layer 2), colE = pre-resolved entity id (layer 1).
// Thread 0 also writes the terminating boundary row_start[8*N] = E.
__global__ void fill_kernel(const int* __restrict__ ei, const int* __restrict__ et,
                            const int* __restrict__ ids,
                            int* __restrict__ cur, int* __restrict__ col,
                            int* __restrict__ colE, int* __restrict__ row_start,
                            int E, int N) {
    int e = blockIdx.x * blockDim.x + threadIdx.x;
    if (e == 0) row_start[RNUM * N] = E;
    if (e < E) {
        int src = ei[e];
        int pos = atomicAdd(&cur[ei[E + e] * RNUM + et[e]], 1);
        col[pos] = src;
        colE[pos] = ids[src];
    }
}

// ---------------- fused layer: r12 structure + work-steal + rotate walk ----------------
// 512 threads, 128-row tiles, As 32 KB + Ws 32 KB (2 blocks/CU).
// Ws(s) staged by global_load_lds at phase START (drains under the walk — never
// adjacent to the barrier). Root row loaded directly at s==8 (r12-verified).
// Walk: 2-deep rotate (edge e+1's row in flight while accumulating edge e).
// Tiles popped via global atomic (no dispatch-round tail).
template <bool HAS_IDX, int ACT>   // ACT: 0 = relu -> bf16 out, 1 = sigmoid -> f32 out
__launch_bounds__(512, 4)
__global__ void rgcn_fused(const int* __restrict__ row_start, const int* __restrict__ col,
                           const int* __restrict__ ids,
                           const unsigned short* __restrict__ x16,
                           const unsigned short* __restrict__ WT,
                           const float* __restrict__ bias,
                           int* __restrict__ tctr, int numTiles,
                           void* __restrict__ CoutV, int N, int E) {
    __shared__ unsigned short As[128 * 128];   // 32 KB
    __shared__ unsigned short Ws[128 * 128];   // 32 KB
    __shared__ int tileShare;

    const int tid = threadIdx.x;
    // MFMA mapping (8 waves: 2 row strips of 64 x 4 col strips of 32)
    const int w = tid >> 6;
    const int lane = tid & 63;
    const int ln15 = lane & 15;
    const int quad = lane >> 4;
    const int rowbase = (w & 1) * 64;
    const int colbase = (w >> 1) * 32;
    // walk mapping: 128 groups of 4 lanes; group g owns row g (64 B per lane)
    const int grp = tid >> 2;
    const int sub4 = tid & 3;

    for (;;) {
        if (tid == 0) tileShare = atomicAdd(tctr, 1);
        __syncthreads();
        const int tile = tileShare;
        if (tile >= numTiles) break;
        const int block0 = tile * 128;
        const int mydst = block0 + grp;
        const bool rowok = (mydst < N);

        float4e acc[4][2];
#pragma unroll
        for (int i = 0; i < 4; i++)
#pragma unroll
            for (int j = 0; j < 2; j++)
#pragma unroll
                for (int q = 0; q < 4; q++) acc[i][j][q] = 0.0f;

#pragma unroll 1
        for (int s = 0; s < RNUM + 1; s++) {
            // ---- stage Ws(s): async DMA at phase start; drains under the walk ----
            {
                const unsigned short* Wsrc = WT + s * 16384;
#pragma unroll
                for (int i = 0; i < 4; i++) {
                    int c = i * 512 + tid;
                    int f = c >> 4;
                    int cc = c & 15;
                    const void* src = (const void*)(Wsrc + f * 128 + ((cc ^ (f & 15)) << 3));
                    int cbase = i * 512 + (tid & ~63);   // wave-uniform base, +lane*16
                    gload_lds16(src, (char*)Ws + (size_t)cbase * 16);
                }
            }
            // ---- stage A tile ----
            if (s < RNUM) {
                float4e a[8];
#pragma unroll
                for (int j = 0; j < 8; j++) a[j] = (float4e){0.f, 0.f, 0.f, 0.f};
                int s0 = 0, s1 = 0;
                if (rowok) {
                    s0 = row_start[mydst * 8 + s];
                    s1 = row_start[mydst * 8 + s + 1];
                }
                const float inv = (s1 > s0) ? 1.0f / (float)(s1 - s0) : 0.0f;
                if (s1 > s0) {
                    // 2-deep rotate: edge e+1's row in flight while accumulating e
                    const uint4* xp = (const uint4*)(x16 + (size_t)col[s0] * HD + sub4 * 32);
                    uint4 w0 = xp[0], w1 = xp[1], w2 = xp[2], w3 = xp[3];
#pragma unroll 1
                    for (int e = s0 + 1; e < s1; e++) {
                        const uint4* xq = (const uint4*)(x16 + (size_t)col[e] * HD + sub4 * 32);
                        uint4 n0 = xq[0], n1 = xq[1], n2 = xq[2], n3 = xq[3];
                        acc2(a[0], w0.x, 0); acc2(a[0], w0.y, 2);
                        acc2(a[1], w0.z, 0); acc2(a[1], w0.w, 2);
                        acc2(a[2], w1.x, 0); acc2(a[2], w1.y, 2);
                        acc2(a[3], w1.z, 0); acc2(a[3], w1.w, 2);
                        acc2(a[4], w2.x, 0); acc2(a[4], w2.y, 2);
                        acc2(a[5], w2.z, 0); acc2(a[5], w2.w, 2);
                        acc2(a[6], w3.x, 0); acc2(a[6], w3.y, 2);
                        acc2(a[7], w3.z, 0); acc2(a[7], w3.w, 2);
                        w0 = n0; w1 = n1; w2 = n2; w3 = n3;
                    }
                    acc2(a[0], w0.x, 0); acc2(a[0], w0.y, 2);
                    acc2(a[1], w0.z, 0); acc2(a[1], w0.w, 2);
                    acc2(a[2], w1.x, 0); acc2(a[2], w1.y, 2);
                    acc2(a[3], w1.z, 0); acc2(a[3], w1.w, 2);
                    acc2(a[4], w2.x, 0); acc2(a[4], w2.y, 2);
                    acc2(a[5], w2.z, 0); acc2(a[5], w2.w, 2);
                    acc2(a[6], w3.x, 0); acc2(a[6], w3.y, 2);
                    acc2(a[7], w3.z, 0); acc2(a[7], w3.w, 2);
                }
#pragma unroll
                for (int j = 0; j < 8; j++) a[j] *= inv;
#pragma unroll
                for (int j = 0; j < 4; j++) {
                    uint4 o;
                    o.x = pk2(a[2 * j][0], a[2 * j][1]);
                    o.y = pk2(a[2 * j][2], a[2 * j][3]);
                    o.z = pk2(a[2 * j + 1][0], a[2 * j + 1][1]);
                    o.w = pk2(a[2 * j + 1][2], a[2 * j + 1][3]);
                    int ck = sub4 * 4 + j;
                    *(uint4*)&As[grp * 128 + ((ck ^ (grp & 15)) << 3)] = o;
                }
            } else {
                // root/self term: bf16 row copy (gather through ids for layer 1)
                uint4 o0 = {0u, 0u, 0u, 0u}, o1 = o0, o2 = o0, o3 = o0;
                if (rowok) {
                    int srcn = HAS_IDX ? ids[mydst] : mydst;
                    const uint4* xp = (const uint4*)(x16 + (size_t)srcn * HD + sub4 * 32);
                    o0 = xp[0]; o1 = xp[1]; o2 = xp[2]; o3 = xp[3];
                }
                const int ck0 = sub4 * 4;
                *(uint4*)&As[grp * 128 + (((ck0 + 0) ^ (grp & 15)) << 3)] = o0;
                *(uint4*)&As[grp * 128 + (((ck0 + 1) ^ (grp & 15)) << 3)] = o1;
                *(uint4*)&As[grp * 128 + (((ck0 + 2) ^ (grp & 15)) << 3)] = o2;
                *(uint4*)&As[grp * 128 + (((ck0 + 3) ^ (grp & 15)) << 3)] = o3;
            }
            __syncthreads();

            // ---- MFMA: A and B from LDS ----
#pragma unroll
            for (int k0 = 0; k0 < 4; k0++) {
                short8 af[4], bf[2];
                const int ck = k0 * 4 + quad;
#pragma unroll
                for (int rt = 0; rt < 4; rt++) {
                    int m = rowbase + rt * 16 + ln15;
                    af[rt] = *(const short8*)&As[m * 128 + ((ck ^ (m & 15)) << 3)];
                }
#pragma unroll
                for (int ct = 0; ct < 2; ct++) {
                    int n = colbase + ct * 16 + ln15;
                    bf[ct] = *(const short8*)&Ws[n * 128 + ((ck ^ (n & 15)) << 3)];
                }
#pragma unroll
                for (int rt = 0; rt < 4; rt++)
#pragma unroll
                    for (int ct = 0; ct < 2; ct++)
                        acc[rt][ct] = __builtin_amdgcn_mfma_f32_16x16x32_bf16(
                            af[rt], bf[ct], acc[rt][ct], 0, 0, 0);
            }
            __syncthreads();
        }

        // ---- epilogue ----
#pragma unroll
        for (int ct = 0; ct < 2; ct++) {
            int ncol = colbase + ct * 16 + ln15;
            float bv = bias[ncol];
#pragma unroll
            for (int rt = 0; rt < 4; rt++) {
#pragma unroll
                for (int rg = 0; rg < 4; rg++) {
                    int rowg = block0 + rowbase + rt * 16 + quad * 4 + rg;
                    if (rowg < N) {
                        float v = acc[rt][ct][rg] + bv;
                        if (ACT == 0) {
                            v = fmaxf(v, 0.0f);
                            ((unsigned short*)CoutV)[(size_t)rowg * HD + ncol] = f2bf(v);
                        } else {
                            v = 1.0f / (1.0f + expf(-v));
                            ((float*)CoutV)[(size_t)rowg * HD + ncol] = v;
                        }
                    }
                }
            }
        }
    }
}

extern "C" void kernel_launch(void* const* d_in, const int* in_sizes, int n_in,
                              void* d_out, int out_size, void* d_ws, size_t ws_size,
                              hipStream_t stream) {
    const int*   x_ids = (const int*)d_in[0];
    const int*   ei    = (const int*)d_in[1];
    const int*   et    = (const int*)d_in[2];
    const float* emb   = (const float*)d_in[3];
    const float* W1    = (const float*)d_in[4];
    const float* root1 = (const float*)d_in[5];
    const float* b1    = (const float*)d_in[6];
    const float* W2    = (const float*)d_in[7];
    const float* root2 = (const float*)d_in[8];
    const float* b2    = (const float*)d_in[9];

    const int N = in_sizes[0];
    const int E = in_sizes[1] / 2;
    const int NS = RNUM * N;
    const long long embElems = (long long)in_sizes[3];   // NUM_ENTITIES * HD
    float* out = (float*)d_out;

    // ---- arenas (row_start has NS+1 entries, padded to 16 B) ----
    char* ws = (char*)d_ws;
    size_t off = 0;
    int* row_start = (int*)(ws + off); off += (size_t)(NS + 4) * 4;             // 3.2 MB
    int* col       = (int*)(ws + off); off += (size_t)E * 4;                    // 2.0 MB
    int* colE      = (int*)(ws + off); off += (size_t)E * 4;                    // 2.0 MB
    int* bsum      = (int*)(ws + off); off += 4096;                             // scan sums + tile ctrs
    unsigned short* WT    = (unsigned short*)(ws + off); off += (size_t)18 * 16384 * 2;
    unsigned short* emb16 = (unsigned short*)(ws + off); off += (size_t)embElems * 2;  // 25.6 MB
    unsigned short* z16   = (unsigned short*)(ws + off); off += (size_t)N * HD * 2;    // 25.6 MB
    int* cur  = (int*)z16;       // alias: cur dead before z16 is first written
    int* tctr = bsum + 1000;     // 2 tile counters (bsum uses only ~400 slots)

    const int scanBlocks = (NS + SCAN_BS - 1) / SCAN_BS;
    const int numTiles = (N + 127) / 128;
    const int layerGrid = (numTiles < 512) ? numTiles : 512;   // 2 blocks/CU, work-stealing

    // ---- CSR build (dst-major) ----
    zero_i<<<(NS + 255) / 256, 256, 0, stream>>>(cur, NS);
    count_kernel<<<(E + 255) / 256, 256, 0, stream>>>(ei, et, cur, E, N);
    scan1<<<scanBlocks, 256, 0, stream>>>(cur, row_start, bsum, NS);
    scan2<<<1, 512, 0, stream>>>(bsum, scanBlocks);
    scan3<<<scanBlocks, 256, 0, stream>>>(row_start, cur, bsum, NS);
    fill_kernel<<<(E + 255) / 256, 256, 0, stream>>>(ei, et, x_ids, cur, col, colE,
                                                     row_start, E, N);

    // ---- weights -> bf16 transposed + emb -> bf16 + zero tile counters (one launch) ----
    {
        long long n8 = embElems / 8;
        long long total = 18 * 16384 + n8;
        prep_kernel<<<(unsigned int)((total + 255) / 256), 256, 0, stream>>>(
            W1, root1, W2, root2, WT, emb, emb16, tctr, n8);
    }

    // ---- layer 1: z16 = bf16(relu(agg(emb16) + emb16[ids]@root1 + b1)) ----
    rgcn_fused<true, 0><<<layerGrid, 512, 0, stream>>>(
        row_start, colE, x_ids, emb16, WT, b1, tctr, numTiles, (void*)z16, N, E);
    // ---- layer 2: out = sigmoid(agg(z16) + z16@root2 + b2) ----
    rgcn_fused<false, 1><<<layerGrid, 512, 0, stream>>>(
        row_start, col, nullptr, z16, WT + 9 * 16384, b2, tctr + 1, numTiles, (void*)out, N, E);
}